// Round 8
// baseline (459.727 us; speedup 1.0000x reference)
//
#include <hip/hip_runtime.h>
#include <stdint.h>

#define M_TOT 2048   // B*C
#define N_TOT 16384  // B*F
#define K_TOT 512    // D

typedef _Float16 f16x8 __attribute__((ext_vector_type(8)));
typedef float f32x16 __attribute__((ext_vector_type(16)));

#define AS1 __attribute__((address_space(1)))
#define AS3 __attribute__((address_space(3)))

__device__ __forceinline__ void ld_lds16(const void* g, void* l) {
    __builtin_amdgcn_global_load_lds((const AS1 void*)g, (AS3 void*)l, 16, 0, 0);
}

#define BAR() do { asm volatile("" ::: "memory"); __builtin_amdgcn_s_barrier(); asm volatile("" ::: "memory"); } while (0)
#define VMC(N) asm volatile("s_waitcnt vmcnt(" #N ")" ::: "memory")

// ---------------- Kernel 1: norms + f16 hi/lo split planes ----------------
__device__ __forceinline__ void split4(float x0, float x1, float x2, float x3,
                                       uint2* hs, uint2* ls) {
    union U { _Float16 h[4]; uint2 u; } H, L;
    _Float16 h0 = (_Float16)x0; H.h[0] = h0; L.h[0] = (_Float16)(x0 - (float)h0);
    _Float16 h1 = (_Float16)x1; H.h[1] = h1; L.h[1] = (_Float16)(x1 - (float)h1);
    _Float16 h2 = (_Float16)x2; H.h[2] = h2; L.h[2] = (_Float16)(x2 - (float)h2);
    _Float16 h3 = (_Float16)x3; H.h[3] = h3; L.h[3] = (_Float16)(x3 - (float)h3);
    *hs = H.u; *ls = L.u;
}

__global__ __launch_bounds__(256) void norm_split_kernel(
    const float* __restrict__ c_feats, const float* __restrict__ f_feats,
    _Float16* __restrict__ Ah, _Float16* __restrict__ Al,
    _Float16* __restrict__ Bh, _Float16* __restrict__ Bl,
    float* __restrict__ normf)
{
    int wave = blockIdx.x * 4 + (threadIdx.x >> 6);
    int lane = threadIdx.x & 63;
    if (wave < 2048) {
        const float* row = c_feats + (size_t)wave * K_TOT;
        float4 v0 = ((const float4*)row)[lane];
        float4 v1 = ((const float4*)row)[lane + 64];
        double ss = (double)v0.x * v0.x + (double)v0.y * v0.y +
                    (double)v0.z * v0.z + (double)v0.w * v0.w +
                    (double)v1.x * v1.x + (double)v1.y * v1.y +
                    (double)v1.z * v1.z + (double)v1.w * v1.w;
        #pragma unroll
        for (int off = 32; off; off >>= 1) ss += __shfl_down(ss, off);
        double tot = __shfl(ss, 0);
        float nrm = sqrtf((float)tot);
        float a0 = v0.x / nrm, a1 = v0.y / nrm, a2 = v0.z / nrm, a3 = v0.w / nrm;
        float b0 = v1.x / nrm, b1 = v1.y / nrm, b2 = v1.z / nrm, b3 = v1.w / nrm;
        uint2 h, l;
        split4(a0, a1, a2, a3, &h, &l);
        ((uint2*)(Ah + (size_t)wave * K_TOT))[lane] = h;
        ((uint2*)(Al + (size_t)wave * K_TOT))[lane] = l;
        split4(b0, b1, b2, b3, &h, &l);
        ((uint2*)(Ah + (size_t)wave * K_TOT))[lane + 64] = h;
        ((uint2*)(Al + (size_t)wave * K_TOT))[lane + 64] = l;
    } else if (wave < 18432) {
        int fr = wave - 2048;
        const float* row = f_feats + (size_t)fr * K_TOT;
        float4 v0 = ((const float4*)row)[lane];
        float4 v1 = ((const float4*)row)[lane + 64];
        double ss = (double)v0.x * v0.x + (double)v0.y * v0.y +
                    (double)v0.z * v0.z + (double)v0.w * v0.w +
                    (double)v1.x * v1.x + (double)v1.y * v1.y +
                    (double)v1.z * v1.z + (double)v1.w * v1.w;
        #pragma unroll
        for (int off = 32; off; off >>= 1) ss += __shfl_down(ss, off);
        if (lane == 0) normf[fr] = sqrtf((float)ss);
        uint2 h, l;
        split4(v0.x, v0.y, v0.z, v0.w, &h, &l);
        ((uint2*)(Bh + (size_t)fr * K_TOT))[lane] = h;
        ((uint2*)(Bl + (size_t)fr * K_TOT))[lane] = l;
        split4(v1.x, v1.y, v1.z, v1.w, &h, &l);
        ((uint2*)(Bh + (size_t)fr * K_TOT))[lane + 64] = h;
        ((uint2*)(Bl + (size_t)fr * K_TOT))[lane + 64] = l;
    }
}

// ---------------- Kernel 2: split-f16 MFMA GEMM, 256x256, 3-phase (R6-proven) ----------------
// R6 version verbatim (best measured total): 256^2 tile, BK=32, 8 waves 2Mx4N,
// dbuf 128 KiB LDS, 3 phases = 3 passes with plane-staggered staging and
// counted vmcnt(4); PH2 reuses PH0/PH1 fragments from registers.
__global__ __launch_bounds__(512, 2) void mfma_gemm_kernel(
    const _Float16* __restrict__ Ah, const _Float16* __restrict__ Al,
    const _Float16* __restrict__ Bh, const _Float16* __restrict__ Bl,
    const float* __restrict__ normf,
    float* __restrict__ out)
{
    __shared__ _Float16 lds[2 * 4 * 8192];   // [buf][plane: Ah,Al,Bh,Bl][256*32]

    const int t = threadIdx.x;
    const int w = t >> 6, lane = t & 63;
    const int m32 = lane & 31, kql0 = lane >> 5;
    const int wr = w >> 2, wc = w & 3;
    const int wm = wr * 128, wn = wc * 64;

    const int bx = (int)blockIdx.x;
    const int ntile = ((bx & 7) << 3) | (bx >> 3);
    const int gm0 = (int)blockIdx.y * 256, gn0 = ntile * 256;

    const int rowA = t >> 2;
    const int kq8 = ((t & 3) ^ ((rowA >> 1) & 3)) * 8;
    const _Float16* const gA   = Ah + (size_t)(gm0 + rowA) * K_TOT + kq8;
    const _Float16* const gB   = Bh + (size_t)(gn0 + rowA) * K_TOT + kq8;
    const _Float16* const gAl2 = gA + (size_t)M_TOT * K_TOT;   // Al plane
    const _Float16* const gBl2 = gB + (size_t)N_TOT * K_TOT;   // Bl plane
    const int t8 = t * 8;

    int aof[4][2], bof[2][2];
    #pragma unroll
    for (int mi = 0; mi < 4; ++mi) {
        int rr = wm + mi * 32 + m32;
        int x = (rr >> 1) & 3;
        #pragma unroll
        for (int kc = 0; kc < 2; ++kc)
            aof[mi][kc] = rr * 32 + (((kc * 2 + kql0) ^ x) * 8);
    }
    #pragma unroll
    for (int ni = 0; ni < 2; ++ni) {
        int rr = wn + ni * 32 + m32;
        int x = (rr >> 1) & 3;
        #pragma unroll
        for (int kc = 0; kc < 2; ++kc)
            bof[ni][kc] = rr * 32 + (((kc * 2 + kql0) ^ x) * 8);
    }

    f32x16 acc[4][2] = {};

    // ---- prologue: stage tile 0 (order: Ah, Bl, Al, Bh) ----
    {
        _Float16* L0 = lds + t8;
        ld_lds16(gA,            L0);
        ld_lds16(gA  + 65536,   L0 + 4096);
        ld_lds16(gBl2,          L0 + 3 * 8192);
        ld_lds16(gBl2 + 65536,  L0 + 3 * 8192 + 4096);
        ld_lds16(gAl2,          L0 + 1 * 8192);
        ld_lds16(gAl2 + 65536,  L0 + 1 * 8192 + 4096);
        ld_lds16(gB,            L0 + 2 * 8192);
        ld_lds16(gB  + 65536,   L0 + 2 * 8192 + 4096);
        VMC(4);          // Ah(0), Bl(0) landed
        BAR();
    }

    #pragma unroll 1
    for (int tt = 0; tt < 16; ++tt) {
        const int cb = (tt & 1) << 15;
        const _Float16* Lc = lds + cb;
        _Float16* Ln = lds + (cb ^ 32768) + t8;
        const int kk = tt * 32 + 32;
        const bool st = (tt < 15);

        f16x8 faH[4][2], fbH[2][2], faL[4][2], fbL[2][2];

        // ==== PH0: pass Ah x Bl ====
        #pragma unroll
        for (int mi = 0; mi < 4; ++mi)
            #pragma unroll
            for (int kc = 0; kc < 2; ++kc)
                faH[mi][kc] = *(const f16x8*)(Lc + aof[mi][kc]);
        #pragma unroll
        for (int ni = 0; ni < 2; ++ni)
            #pragma unroll
            for (int kc = 0; kc < 2; ++kc)
                fbL[ni][kc] = *(const f16x8*)(Lc + 3 * 8192 + bof[ni][kc]);
        if (st) {
            ld_lds16(gA + kk,         Ln);
            ld_lds16(gA + kk + 65536, Ln + 4096);
            ld_lds16(gBl2 + kk,         Ln + 3 * 8192);
            ld_lds16(gBl2 + kk + 65536, Ln + 3 * 8192 + 4096);
        }
        BAR();
        __builtin_amdgcn_s_setprio(1);
        #pragma unroll
        for (int mi = 0; mi < 4; ++mi)
            #pragma unroll
            for (int ni = 0; ni < 2; ++ni)
                #pragma unroll
                for (int kc = 0; kc < 2; ++kc)
                    acc[mi][ni] = __builtin_amdgcn_mfma_f32_32x32x16_f16(
                        faH[mi][kc], fbL[ni][kc], acc[mi][ni], 0, 0, 0);
        __builtin_amdgcn_s_setprio(0);
        if (st) VMC(4); else VMC(2);   // Al(t), Bh(t) landed
        BAR();

        // ==== PH1: pass Al x Bh ====
        #pragma unroll
        for (int mi = 0; mi < 4; ++mi)
            #pragma unroll
            for (int kc = 0; kc < 2; ++kc)
                faL[mi][kc] = *(const f16x8*)(Lc + 1 * 8192 + aof[mi][kc]);
        #pragma unroll
        for (int ni = 0; ni < 2; ++ni)
            #pragma unroll
            for (int kc = 0; kc < 2; ++kc)
                fbH[ni][kc] = *(const f16x8*)(Lc + 2 * 8192 + bof[ni][kc]);
        if (st) {
            ld_lds16(gAl2 + kk,         Ln + 1 * 8192);
            ld_lds16(gAl2 + kk + 65536, Ln + 1 * 8192 + 4096);
            ld_lds16(gB   + kk,         Ln + 2 * 8192);
            ld_lds16(gB   + kk + 65536, Ln + 2 * 8192 + 4096);
        }
        BAR();
        __builtin_amdgcn_s_setprio(1);
        #pragma unroll
        for (int mi = 0; mi < 4; ++mi)
            #pragma unroll
            for (int ni = 0; ni < 2; ++ni)
                #pragma unroll
                for (int kc = 0; kc < 2; ++kc)
                    acc[mi][ni] = __builtin_amdgcn_mfma_f32_32x32x16_f16(
                        faL[mi][kc], fbH[ni][kc], acc[mi][ni], 0, 0, 0);
        __builtin_amdgcn_s_setprio(0);
        BAR();

        // ==== PH2: pass Ah x Bh (register reuse, no LDS) ====
        __builtin_amdgcn_s_setprio(1);
        #pragma unroll
        for (int mi = 0; mi < 4; ++mi)
            #pragma unroll
            for (int ni = 0; ni < 2; ++ni)
                #pragma unroll
                for (int kc = 0; kc < 2; ++kc)
                    acc[mi][ni] = __builtin_amdgcn_mfma_f32_32x32x16_f16(
                        faH[mi][kc], fbH[ni][kc], acc[mi][ni], 0, 0, 0);
        __builtin_amdgcn_s_setprio(0);
        if (st) VMC(4);                // Ah(t+1), Bl(t+1) landed for next PH0
        BAR();
    }

    // ---- epilogue: norm-correct + store ----
    const int rq = 4 * kql0;
    #pragma unroll
    for (int ni = 0; ni < 2; ++ni) {
        const int gc = gn0 + wn + ni * 32 + m32;
        const int nn = gc >> 7;
        const int col = gc & 127;
        const bool cn = (col < 16);
        const float nf = cn ? normf[gc] : 1.f;
        #pragma unroll
        for (int mi = 0; mi < 4; ++mi) {
            #pragma unroll
            for (int reg = 0; reg < 16; ++reg) {
                const int gm = gm0 + wm + mi * 32 + (reg & 3) + 8 * (reg >> 2) + rq;
                const int mm = gm >> 4, ii = gm & 15;
                float v = acc[mi][ni][reg];
                if (cn && col <= ii) v /= nf;
                out[(((size_t)mm * 128 + nn) * 16 + ii) * 128 + col] = v;
            }
        }
    }
}

// ---------------- Kernel 3: wavefront DTW, full-prestage (2 wait-points) ----------------
// R8: all 8 windows staged to LDS BEFORE the DP, in two 16-load register
// batches -> 2 vmcnt wait-points per wave instead of ~7. Rationale: per-wave
// residence was 74us vs 2.6us of issue; each staging wait pays VMEM QUEUE
// delay (~10us under ~2000 resident waves), not nominal latency -- which is
// why prefetch depth (R7) and granularity (R5) were both null. DP loop now has
// zero interleaved global memory. Window stride WBUF == 0 (mod 32) preserves
// the proven conflict-free banking; sv addressing otherwise identical.
#define WQS 304        // per-problem stride (floats): 16*18 + 16 (==16 mod 32)
#define WBUF 1216      // per-window stride: 4 problems * WQS

__device__ __forceinline__ float dpp_shr1_f32(float x) {
    union { float f; int i; } u, v;
    u.f = x;
    v.i = __builtin_amdgcn_update_dpp(u.i, u.i, 0x111, 0xF, 0xF, false);
    return v.f;
}

__global__ __launch_bounds__(64) void dtw_kernel(float* __restrict__ buf)
{
    __shared__ float swin[8 * WBUF];     // 38912 B (all 8 windows x 4 problems)
    __shared__ uint32_t mvw[4][132];     // 2112 B
    __shared__ int bounds[4][16];        // 256 B   -> 41280 B, 3 blocks/CU

    const int lane = threadIdx.x & 63;
    const int q = lane >> 4, r = lane & 15;
    const int pbase = (4095 - (int)blockIdx.x) * 4;
    const float4* gbase = (const float4*)(buf + (size_t)pbase * 2048);
    float* sw = swin;
    uint32_t* mvq = &mvw[q][0];

    int gidx[4], lidx[4];
    #pragma unroll
    for (int i = 0; i < 4; ++i) {
        gidx[i] = i * 512 + ((lane >> 2) & 15) * 32 + (lane & 3);
        lidx[i] = i * WQS + ((lane >> 2) & 15) * 18 + (lane & 3) * 4;
    }

#define WSTORE(regs, boff)                                                      \
    {                                                                           \
        _Pragma("unroll")                                                       \
        for (int i = 0; i < 4; ++i) {                                           \
            *(float2*)(sw + (boff) + lidx[i])     = make_float2(regs[i].x, regs[i].y); \
            *(float2*)(sw + (boff) + lidx[i] + 2) = make_float2(regs[i].z, regs[i].w); \
        }                                                                       \
    }
#define WLOAD(regs, win)                                                        \
    {                                                                           \
        _Pragma("unroll")                                                       \
        for (int i = 0; i < 4; ++i) regs[i] = gbase[gidx[i] + (win) * 4];       \
    }

    // ---- stage ALL windows: 2 batches, 2 wait-points ----
    float4 Wa[4], Wb[4], Wc[4], Wd[4];
    WLOAD(Wa, 0) WLOAD(Wb, 1) WLOAD(Wc, 2) WLOAD(Wd, 3)
    WSTORE(Wa, 0)         WSTORE(Wb, WBUF)
    WSTORE(Wc, 2 * WBUF)  WSTORE(Wd, 3 * WBUF)
    WLOAD(Wa, 4) WLOAD(Wb, 5) WLOAD(Wc, 6) WLOAD(Wd, 7)
    WSTORE(Wa, 4 * WBUF)  WSTORE(Wb, 5 * WBUF)
    WSTORE(Wc, 6 * WBUF)  WSTORE(Wd, 7 * WBUF)

    const float NEG = -1e30f;
    float Dp = NEG, rawprev = NEG;
    uint32_t mvbuf = 0;
    int j = -r;
    const int sb = q * WQS + r * 18;

#define DTW_STEP(BOUNDARY)                                                      \
    {                                                                           \
        float upr = dpp_shr1_f32(Dp);                                           \
        float dg = rawprev;                                                     \
        rawprev = upr;                                                          \
        float up = (r == 0) ? NEG : upr;                                        \
        float lf = Dp;                                                          \
        if (BOUNDARY) {                                                         \
            if (j == 0) { lf = NEG; dg = (r == 0) ? 0.0f : NEG; }               \
            else if (r == 0) dg = NEG;                                          \
        } else {                                                                \
            if (r == 0) dg = NEG;                                               \
        }                                                                       \
        float sv = sw[((j >> 4) & 7) * WBUF + sb + (j & 15)];                   \
        int m = (up >= lf && up >= dg) ? 0 : ((lf >= dg) ? 1 : 2);              \
        float Dc = fmaxf(up, fmaxf(lf, dg)) + sv;                               \
        if ((unsigned)j < 128u) {                                               \
            mvbuf |= (uint32_t)m << (2 * (j & 15));                             \
            if ((j & 15) == 15) { mvq[r * 8 + (j >> 4)] = mvbuf; mvbuf = 0; }   \
        }                                                                       \
        Dp = Dc;                                                                \
        ++j;                                                                    \
    }

    for (int tt = 0; tt < 16; ++tt) DTW_STEP(true)
    for (int tt = 16; tt < 143; ++tt) DTW_STEP(false)
#undef DTW_STEP
#undef WSTORE
#undef WLOAD

    __syncthreads();   // single-wave: cheap; orders mv writes vs leader reads

    // backtrack: leader lanes (0,16,32,48), word-cached move decode
    if (r == 0) {
        int i = 16, jj = 128, hic = 127;
        int cidx = -1;
        uint32_t word = 0;
        for (int it = 0; it < 160; ++it) {
            if (i <= 0) break;
            int idx = (i - 1) * 8 + ((jj - 1) >> 4);
            if (idx != cidx) { word = mvq[idx]; cidx = idx; }
            int m = (int)((word >> (2 * ((jj - 1) & 15))) & 3u);
            if (m == 1) { --jj; continue; }
            bounds[q][i - 1] = (jj - 1) | (hic << 8);
            if (m == 2) --jj;
            --i;
            hic = jj - 1;
        }
    }
    __syncthreads();

    // write masks: 4 problems * 2048 floats = 2048 float4, coalesced
    #pragma unroll 4
    for (int it = 0; it < 32; ++it) {
        int flat = it * 64 + lane;
        int q2 = flat >> 9;
        int rem = flat & 511;
        int ii = rem >> 5;
        int c4 = rem & 31;
        int b = bounds[q2][ii];
        int lo = b & 0xff, hi = (b >> 8) & 0xff;
        int j0 = c4 * 4;
        float4 v;
        v.x = (j0 + 0 >= lo && j0 + 0 <= hi) ? 1.f : 0.f;
        v.y = (j0 + 1 >= lo && j0 + 1 <= hi) ? 1.f : 0.f;
        v.z = (j0 + 2 >= lo && j0 + 2 <= hi) ? 1.f : 0.f;
        v.w = (j0 + 3 >= lo && j0 + 3 <= hi) ? 1.f : 0.f;
        float* tb = buf + (size_t)(pbase + q2) * 2048;
        *(float4*)(tb + ii * 128 + j0) = v;
    }
}

extern "C" void kernel_launch(void* const* d_in, const int* in_sizes, int n_in,
                              void* d_out, int out_size, void* d_ws, size_t ws_size,
                              hipStream_t stream)
{
    const float* c_feats = (const float*)d_in[0];
    const float* f_feats = (const float*)d_in[1];
    float* out = (float*)d_out;

    _Float16* Ah = (_Float16*)d_ws;
    _Float16* Al = Ah + (size_t)M_TOT * K_TOT;
    _Float16* Bh = Al + (size_t)M_TOT * K_TOT;
    _Float16* Bl = Bh + (size_t)N_TOT * K_TOT;
    float* normf = (float*)(Bl + (size_t)N_TOT * K_TOT);

    norm_split_kernel<<<4608, 256, 0, stream>>>(c_feats, f_feats, Ah, Al, Bh, Bl, normf);
    dim3 g(N_TOT / 256, M_TOT / 256);
    mfma_gemm_kernel<<<g, 512, 0, stream>>>(Ah, Al, Bh, Bl, normf, out);
    dtw_kernel<<<4096, 64, 0, stream>>>(out);
}

// Round 9
// 330.804 us; speedup vs baseline: 1.3897x; 1.3897x over previous
//
#include <hip/hip_runtime.h>
#include <stdint.h>

#define M_TOT 2048   // B*C
#define N_TOT 16384  // B*F
#define K_TOT 512    // D

typedef _Float16 f16x8 __attribute__((ext_vector_type(8)));
typedef float f32x16 __attribute__((ext_vector_type(16)));

#define AS1 __attribute__((address_space(1)))
#define AS3 __attribute__((address_space(3)))

__device__ __forceinline__ void ld_lds16(const void* g, void* l) {
    __builtin_amdgcn_global_load_lds((const AS1 void*)g, (AS3 void*)l, 16, 0, 0);
}

#define BAR() do { asm volatile("" ::: "memory"); __builtin_amdgcn_s_barrier(); asm volatile("" ::: "memory"); } while (0)
#define VMC(N) asm volatile("s_waitcnt vmcnt(" #N ")" ::: "memory")

// ---------------- Kernel 1: norms + f16 hi/lo split planes ----------------
__device__ __forceinline__ void split4(float x0, float x1, float x2, float x3,
                                       uint2* hs, uint2* ls) {
    union U { _Float16 h[4]; uint2 u; } H, L;
    _Float16 h0 = (_Float16)x0; H.h[0] = h0; L.h[0] = (_Float16)(x0 - (float)h0);
    _Float16 h1 = (_Float16)x1; H.h[1] = h1; L.h[1] = (_Float16)(x1 - (float)h1);
    _Float16 h2 = (_Float16)x2; H.h[2] = h2; L.h[2] = (_Float16)(x2 - (float)h2);
    _Float16 h3 = (_Float16)x3; H.h[3] = h3; L.h[3] = (_Float16)(x3 - (float)h3);
    *hs = H.u; *ls = L.u;
}

__global__ __launch_bounds__(256) void norm_split_kernel(
    const float* __restrict__ c_feats, const float* __restrict__ f_feats,
    _Float16* __restrict__ Ah, _Float16* __restrict__ Al,
    _Float16* __restrict__ Bh, _Float16* __restrict__ Bl,
    float* __restrict__ normf)
{
    int wave = blockIdx.x * 4 + (threadIdx.x >> 6);
    int lane = threadIdx.x & 63;
    if (wave < 2048) {
        const float* row = c_feats + (size_t)wave * K_TOT;
        float4 v0 = ((const float4*)row)[lane];
        float4 v1 = ((const float4*)row)[lane + 64];
        double ss = (double)v0.x * v0.x + (double)v0.y * v0.y +
                    (double)v0.z * v0.z + (double)v0.w * v0.w +
                    (double)v1.x * v1.x + (double)v1.y * v1.y +
                    (double)v1.z * v1.z + (double)v1.w * v1.w;
        #pragma unroll
        for (int off = 32; off; off >>= 1) ss += __shfl_down(ss, off);
        double tot = __shfl(ss, 0);
        float nrm = sqrtf((float)tot);
        float a0 = v0.x / nrm, a1 = v0.y / nrm, a2 = v0.z / nrm, a3 = v0.w / nrm;
        float b0 = v1.x / nrm, b1 = v1.y / nrm, b2 = v1.z / nrm, b3 = v1.w / nrm;
        uint2 h, l;
        split4(a0, a1, a2, a3, &h, &l);
        ((uint2*)(Ah + (size_t)wave * K_TOT))[lane] = h;
        ((uint2*)(Al + (size_t)wave * K_TOT))[lane] = l;
        split4(b0, b1, b2, b3, &h, &l);
        ((uint2*)(Ah + (size_t)wave * K_TOT))[lane + 64] = h;
        ((uint2*)(Al + (size_t)wave * K_TOT))[lane + 64] = l;
    } else if (wave < 18432) {
        int fr = wave - 2048;
        const float* row = f_feats + (size_t)fr * K_TOT;
        float4 v0 = ((const float4*)row)[lane];
        float4 v1 = ((const float4*)row)[lane + 64];
        double ss = (double)v0.x * v0.x + (double)v0.y * v0.y +
                    (double)v0.z * v0.z + (double)v0.w * v0.w +
                    (double)v1.x * v1.x + (double)v1.y * v1.y +
                    (double)v1.z * v1.z + (double)v1.w * v1.w;
        #pragma unroll
        for (int off = 32; off; off >>= 1) ss += __shfl_down(ss, off);
        if (lane == 0) normf[fr] = sqrtf((float)ss);
        uint2 h, l;
        split4(v0.x, v0.y, v0.z, v0.w, &h, &l);
        ((uint2*)(Bh + (size_t)fr * K_TOT))[lane] = h;
        ((uint2*)(Bl + (size_t)fr * K_TOT))[lane] = l;
        split4(v1.x, v1.y, v1.z, v1.w, &h, &l);
        ((uint2*)(Bh + (size_t)fr * K_TOT))[lane + 64] = h;
        ((uint2*)(Bl + (size_t)fr * K_TOT))[lane + 64] = l;
    }
}

// ---------------- Kernel 2: split-f16 MFMA GEMM, 256x256, 3-phase (R6-proven) ----------------
// R6 version; ONLY change (R9): the epilogue writes S in per-problem
// WINDOW-MAJOR layout  S'[P][w 8][ii 16][c 16]  (addr = P*2048 + w*256 +
// ii*16 + c) so the DTW kernel's window reads become fully-contiguous 1KB
// transactions. Values unchanged.
__global__ __launch_bounds__(512, 2) void mfma_gemm_kernel(
    const _Float16* __restrict__ Ah, const _Float16* __restrict__ Al,
    const _Float16* __restrict__ Bh, const _Float16* __restrict__ Bl,
    const float* __restrict__ normf,
    float* __restrict__ out)
{
    __shared__ _Float16 lds[2 * 4 * 8192];   // [buf][plane: Ah,Al,Bh,Bl][256*32]

    const int t = threadIdx.x;
    const int w = t >> 6, lane = t & 63;
    const int m32 = lane & 31, kql0 = lane >> 5;
    const int wr = w >> 2, wc = w & 3;
    const int wm = wr * 128, wn = wc * 64;

    const int bx = (int)blockIdx.x;
    const int ntile = ((bx & 7) << 3) | (bx >> 3);
    const int gm0 = (int)blockIdx.y * 256, gn0 = ntile * 256;

    const int rowA = t >> 2;
    const int kq8 = ((t & 3) ^ ((rowA >> 1) & 3)) * 8;
    const _Float16* const gA   = Ah + (size_t)(gm0 + rowA) * K_TOT + kq8;
    const _Float16* const gB   = Bh + (size_t)(gn0 + rowA) * K_TOT + kq8;
    const _Float16* const gAl2 = gA + (size_t)M_TOT * K_TOT;   // Al plane
    const _Float16* const gBl2 = gB + (size_t)N_TOT * K_TOT;   // Bl plane
    const int t8 = t * 8;

    int aof[4][2], bof[2][2];
    #pragma unroll
    for (int mi = 0; mi < 4; ++mi) {
        int rr = wm + mi * 32 + m32;
        int x = (rr >> 1) & 3;
        #pragma unroll
        for (int kc = 0; kc < 2; ++kc)
            aof[mi][kc] = rr * 32 + (((kc * 2 + kql0) ^ x) * 8);
    }
    #pragma unroll
    for (int ni = 0; ni < 2; ++ni) {
        int rr = wn + ni * 32 + m32;
        int x = (rr >> 1) & 3;
        #pragma unroll
        for (int kc = 0; kc < 2; ++kc)
            bof[ni][kc] = rr * 32 + (((kc * 2 + kql0) ^ x) * 8);
    }

    f32x16 acc[4][2] = {};

    // ---- prologue: stage tile 0 (order: Ah, Bl, Al, Bh) ----
    {
        _Float16* L0 = lds + t8;
        ld_lds16(gA,            L0);
        ld_lds16(gA  + 65536,   L0 + 4096);
        ld_lds16(gBl2,          L0 + 3 * 8192);
        ld_lds16(gBl2 + 65536,  L0 + 3 * 8192 + 4096);
        ld_lds16(gAl2,          L0 + 1 * 8192);
        ld_lds16(gAl2 + 65536,  L0 + 1 * 8192 + 4096);
        ld_lds16(gB,            L0 + 2 * 8192);
        ld_lds16(gB  + 65536,   L0 + 2 * 8192 + 4096);
        VMC(4);          // Ah(0), Bl(0) landed
        BAR();
    }

    #pragma unroll 1
    for (int tt = 0; tt < 16; ++tt) {
        const int cb = (tt & 1) << 15;
        const _Float16* Lc = lds + cb;
        _Float16* Ln = lds + (cb ^ 32768) + t8;
        const int kk = tt * 32 + 32;
        const bool st = (tt < 15);

        f16x8 faH[4][2], fbH[2][2], faL[4][2], fbL[2][2];

        // ==== PH0: pass Ah x Bl ====
        #pragma unroll
        for (int mi = 0; mi < 4; ++mi)
            #pragma unroll
            for (int kc = 0; kc < 2; ++kc)
                faH[mi][kc] = *(const f16x8*)(Lc + aof[mi][kc]);
        #pragma unroll
        for (int ni = 0; ni < 2; ++ni)
            #pragma unroll
            for (int kc = 0; kc < 2; ++kc)
                fbL[ni][kc] = *(const f16x8*)(Lc + 3 * 8192 + bof[ni][kc]);
        if (st) {
            ld_lds16(gA + kk,         Ln);
            ld_lds16(gA + kk + 65536, Ln + 4096);
            ld_lds16(gBl2 + kk,         Ln + 3 * 8192);
            ld_lds16(gBl2 + kk + 65536, Ln + 3 * 8192 + 4096);
        }
        BAR();
        __builtin_amdgcn_s_setprio(1);
        #pragma unroll
        for (int mi = 0; mi < 4; ++mi)
            #pragma unroll
            for (int ni = 0; ni < 2; ++ni)
                #pragma unroll
                for (int kc = 0; kc < 2; ++kc)
                    acc[mi][ni] = __builtin_amdgcn_mfma_f32_32x32x16_f16(
                        faH[mi][kc], fbL[ni][kc], acc[mi][ni], 0, 0, 0);
        __builtin_amdgcn_s_setprio(0);
        if (st) VMC(4); else VMC(2);   // Al(t), Bh(t) landed
        BAR();

        // ==== PH1: pass Al x Bh ====
        #pragma unroll
        for (int mi = 0; mi < 4; ++mi)
            #pragma unroll
            for (int kc = 0; kc < 2; ++kc)
                faL[mi][kc] = *(const f16x8*)(Lc + 1 * 8192 + aof[mi][kc]);
        #pragma unroll
        for (int ni = 0; ni < 2; ++ni)
            #pragma unroll
            for (int kc = 0; kc < 2; ++kc)
                fbH[ni][kc] = *(const f16x8*)(Lc + 2 * 8192 + bof[ni][kc]);
        if (st) {
            ld_lds16(gAl2 + kk,         Ln + 1 * 8192);
            ld_lds16(gAl2 + kk + 65536, Ln + 1 * 8192 + 4096);
            ld_lds16(gB   + kk,         Ln + 2 * 8192);
            ld_lds16(gB   + kk + 65536, Ln + 2 * 8192 + 4096);
        }
        BAR();
        __builtin_amdgcn_s_setprio(1);
        #pragma unroll
        for (int mi = 0; mi < 4; ++mi)
            #pragma unroll
            for (int ni = 0; ni < 2; ++ni)
                #pragma unroll
                for (int kc = 0; kc < 2; ++kc)
                    acc[mi][ni] = __builtin_amdgcn_mfma_f32_32x32x16_f16(
                        faL[mi][kc], fbH[ni][kc], acc[mi][ni], 0, 0, 0);
        __builtin_amdgcn_s_setprio(0);
        BAR();

        // ==== PH2: pass Ah x Bh (register reuse, no LDS) ====
        __builtin_amdgcn_s_setprio(1);
        #pragma unroll
        for (int mi = 0; mi < 4; ++mi)
            #pragma unroll
            for (int ni = 0; ni < 2; ++ni)
                #pragma unroll
                for (int kc = 0; kc < 2; ++kc)
                    acc[mi][ni] = __builtin_amdgcn_mfma_f32_32x32x16_f16(
                        faH[mi][kc], fbH[ni][kc], acc[mi][ni], 0, 0, 0);
        __builtin_amdgcn_s_setprio(0);
        if (st) VMC(4);                // Ah(t+1), Bl(t+1) landed for next PH0
        BAR();
    }

    // ---- epilogue: norm-correct + store S in window-major layout ----
    const int rq = 4 * kql0;
    #pragma unroll
    for (int ni = 0; ni < 2; ++ni) {
        const int gc = gn0 + wn + ni * 32 + m32;
        const int nn = gc >> 7;
        const int col = gc & 127;
        const bool cn = (col < 16);
        const float nf = cn ? normf[gc] : 1.f;
        #pragma unroll
        for (int mi = 0; mi < 4; ++mi) {
            #pragma unroll
            for (int reg = 0; reg < 16; ++reg) {
                const int gm = gm0 + wm + mi * 32 + (reg & 3) + 8 * (reg >> 2) + rq;
                const int mm = gm >> 4, ii = gm & 15;
                float v = acc[mi][ni][reg];
                if (cn && col <= ii) v /= nf;
                out[(size_t)(mm * 128 + nn) * 2048 +
                    ((col >> 4) * 256 + ii * 16 + (col & 15))] = v;
            }
        }
    }
}

// ---------------- Kernel 3: wavefront DTW, coalesced LDS-DMA staging ----------------
// R9: S is now window-major per problem (GEMM epilogue), so each window read is
// ONE fully-contiguous 1KB global_load_lds per problem (vs 16 scattered 64B
// segments). 4-slot LDS ring: slots 0-3 hold windows w&3; windows 0-3 issued
// up-front, win w+4 issued right after the last win-w read (T=16w+30);
// counted vmcnt(8) per window boundary, no VGPR staging (R7's register ring
// was compiler-serialized: VGPR=60). Banking: addr = slot*1056 + q*264 +
// r*16 + ((T-r)&15); 264==8 (mod 32), r*16 + (T-r)&15 gives 16 distinct banks
// per q-group, q-offsets {0,8,16,24} -> exactly 2 lanes/bank (free, m136).
// LDS 19.3KB -> 8 blocks/CU (= measured resident). DP/backtrack/mask-write
// identical; prefix (j<0) and tail (j>=128) garbage reads land in valid slots
// and are masked exactly as before -> absmax 0.
#define SLOT 264       // per-problem stride (floats): 256 + 8  (==8 mod 32)
#define WSLOT 1056     // per-window-slot stride: 4*SLOT (==0 mod 32)

__device__ __forceinline__ float dpp_shr1_f32(float x) {
    union { float f; int i; } u, v;
    u.f = x;
    v.i = __builtin_amdgcn_update_dpp(u.i, u.i, 0x111, 0xF, 0xF, false);
    return v.f;
}

__global__ __launch_bounds__(64) void dtw_kernel(float* __restrict__ buf)
{
    __shared__ float swin[4 * WSLOT];    // 16896 B (4-slot window ring)
    __shared__ uint32_t mvw[4][132];     // 2112 B
    __shared__ int bounds[4][16];        // 256 B   -> 19264 B, 8 blocks/CU

    const int lane = threadIdx.x & 63;
    const int q = lane >> 4, r = lane & 15;
    const int pbase = (4095 - (int)blockIdx.x) * 4;
    const float4* gb4 = (const float4*)(buf + (size_t)pbase * 2048);
    uint32_t* mvq = &mvw[q][0];

    // stage window WN (4 problems): 1KB contiguous per problem; LDS dest is
    // wave-uniform (HW adds lane*16B) -> linear [r 16][t 16] layout per slot.
#define STAGE(WN)                                                               \
    {                                                                           \
        _Pragma("unroll")                                                       \
        for (int p_ = 0; p_ < 4; ++p_)                                          \
            ld_lds16(gb4 + p_ * 512 + (WN) * 64 + lane,                         \
                     swin + ((WN) & 3) * WSLOT + p_ * SLOT);                    \
    }

    STAGE(0) STAGE(1) STAGE(2) STAGE(3)
    VMC(12);   // win0 landed; 12 in flight

    const float NEG = -1e30f;
    float Dp = NEG, rawprev = NEG;
    uint32_t mvbuf = 0;
    int j = -r;
    const int sb = q * SLOT + r * 16;

#define DTW_STEP(BOUNDARY)                                                      \
    {                                                                           \
        float upr = dpp_shr1_f32(Dp);                                           \
        float dg = rawprev;                                                     \
        rawprev = upr;                                                          \
        float up = (r == 0) ? NEG : upr;                                        \
        float lf = Dp;                                                          \
        if (BOUNDARY) {                                                         \
            if (j == 0) { lf = NEG; dg = (r == 0) ? 0.0f : NEG; }               \
            else if (r == 0) dg = NEG;                                          \
        } else {                                                                \
            if (r == 0) dg = NEG;                                               \
        }                                                                       \
        float sv = swin[((j >> 4) & 3) * WSLOT + sb + (j & 15)];                \
        int m = (up >= lf && up >= dg) ? 0 : ((lf >= dg) ? 1 : 2);              \
        float Dc = fmaxf(up, fmaxf(lf, dg)) + sv;                               \
        if ((unsigned)j < 128u) {                                               \
            mvbuf |= (uint32_t)m << (2 * (j & 15));                             \
            if ((j & 15) == 15) { mvq[r * 8 + (j >> 4)] = mvbuf; mvbuf = 0; }   \
        }                                                                       \
        Dp = Dc;                                                                \
        ++j;                                                                    \
    }

    for (int tt = 0; tt < 16; ++tt) DTW_STEP(true)        // T=0..15
    VMC(8);                                               // win1 landed
    for (int tt = 16; tt < 31; ++tt) DTW_STEP(false)      // T=16..30
    STAGE(4)                                              // slot0 free after T=30
    DTW_STEP(false)                                       // T=31
    VMC(8);                                               // win2 landed
    for (int tt = 32; tt < 47; ++tt) DTW_STEP(false)      // T=32..46
    STAGE(5)                                              // slot1 free after T=46
    DTW_STEP(false)                                       // T=47
    VMC(8);                                               // win3 landed
    for (int tt = 48; tt < 63; ++tt) DTW_STEP(false)      // T=48..62
    STAGE(6)                                              // slot2 free after T=62
    DTW_STEP(false)                                       // T=63
    VMC(8);                                               // win4 landed
    for (int tt = 64; tt < 79; ++tt) DTW_STEP(false)      // T=64..78
    STAGE(7)                                              // slot3 free after T=78
    DTW_STEP(false)                                       // T=79
    VMC(8);                                               // win5 landed
    for (int tt = 80; tt < 96; ++tt) DTW_STEP(false)      // T=80..95
    VMC(4);                                               // win6 landed
    for (int tt = 96; tt < 112; ++tt) DTW_STEP(false)     // T=96..111
    VMC(0);                                               // win7 landed
    for (int tt = 112; tt < 143; ++tt) DTW_STEP(false)    // T=112..142
#undef DTW_STEP
#undef STAGE

    __syncthreads();   // single-wave: cheap; orders mv writes vs leader reads

    // backtrack: leader lanes (0,16,32,48), word-cached move decode
    if (r == 0) {
        int i = 16, jj = 128, hic = 127;
        int cidx = -1;
        uint32_t word = 0;
        for (int it = 0; it < 160; ++it) {
            if (i <= 0) break;
            int idx = (i - 1) * 8 + ((jj - 1) >> 4);
            if (idx != cidx) { word = mvq[idx]; cidx = idx; }
            int m = (int)((word >> (2 * ((jj - 1) & 15))) & 3u);
            if (m == 1) { --jj; continue; }
            bounds[q][i - 1] = (jj - 1) | (hic << 8);
            if (m == 2) --jj;
            --i;
            hic = jj - 1;
        }
    }
    __syncthreads();

    // write masks: 4 problems * 2048 floats = 2048 float4, coalesced
    #pragma unroll 4
    for (int it = 0; it < 32; ++it) {
        int flat = it * 64 + lane;
        int q2 = flat >> 9;
        int rem = flat & 511;
        int ii = rem >> 5;
        int c4 = rem & 31;
        int b = bounds[q2][ii];
        int lo = b & 0xff, hi = (b >> 8) & 0xff;
        int j0 = c4 * 4;
        float4 v;
        v.x = (j0 + 0 >= lo && j0 + 0 <= hi) ? 1.f : 0.f;
        v.y = (j0 + 1 >= lo && j0 + 1 <= hi) ? 1.f : 0.f;
        v.z = (j0 + 2 >= lo && j0 + 2 <= hi) ? 1.f : 0.f;
        v.w = (j0 + 3 >= lo && j0 + 3 <= hi) ? 1.f : 0.f;
        float* tb = buf + (size_t)(pbase + q2) * 2048;
        *(float4*)(tb + ii * 128 + j0) = v;
    }
}

extern "C" void kernel_launch(void* const* d_in, const int* in_sizes, int n_in,
                              void* d_out, int out_size, void* d_ws, size_t ws_size,
                              hipStream_t stream)
{
    const float* c_feats = (const float*)d_in[0];
    const float* f_feats = (const float*)d_in[1];
    float* out = (float*)d_out;

    _Float16* Ah = (_Float16*)d_ws;
    _Float16* Al = Ah + (size_t)M_TOT * K_TOT;
    _Float16* Bh = Al + (size_t)M_TOT * K_TOT;
    _Float16* Bl = Bh + (size_t)N_TOT * K_TOT;
    float* normf = (float*)(Bl + (size_t)N_TOT * K_TOT);

    norm_split_kernel<<<4608, 256, 0, stream>>>(c_feats, f_feats, Ah, Al, Bh, Bl, normf);
    dim3 g(N_TOT / 256, M_TOT / 256);
    mfma_gemm_kernel<<<g, 512, 0, stream>>>(Ah, Al, Bh, Bl, normf, out);
    dtw_kernel<<<4096, 64, 0, stream>>>(out);
}